// Round 5
// baseline (654.789 us; speedup 1.0000x reference)
//
#include <hip/hip_runtime.h>
#include <math.h>

// Problem constants
constexpr int B_ = 4, C_ = 192, N_ = 160, M_ = 160;
constexpr int NM_ = N_ * M_;            // 25600
constexpr float SQRT_C = 13.856406460551018f;   // sqrt(192)
constexpr float SCALE_ = 0.17677669529663687f;  // 1/sqrt(32)
constexpr int NBLK = 512;               // persistent grid: 2 blocks/CU x 256 CUs

__device__ __forceinline__ float wred_sum(float v) {
    #pragma unroll
    for (int o = 32; o > 0; o >>= 1) v += __shfl_xor(v, o, 64);
    return v;
}
__device__ __forceinline__ float wred_max(float v) {
    #pragma unroll
    for (int o = 32; o > 0; o >>= 1) v = fmaxf(v, __shfl_xor(v, o, 64));
    return v;
}

// Device-wide barrier: one distinct counter per phase (no reset -> no races).
// Counters are zeroed by hipMemsetAsync before launch.
__device__ __forceinline__ void gridbar(int* cnt) {
    __syncthreads();
    if (threadIdx.x == 0) {
        __threadfence();  // release: make this block's global writes visible
        __hip_atomic_fetch_add(cnt, 1, __ATOMIC_RELEASE, __HIP_MEMORY_SCOPE_AGENT);
        while (__hip_atomic_load(cnt, __ATOMIC_RELAXED, __HIP_MEMORY_SCOPE_AGENT) < NBLK)
            __builtin_amdgcn_s_sleep(4);
    }
    __syncthreads();
    __threadfence();      // acquire: invalidate caches before reading others' data
}

// ONE persistent kernel, 6 phases, 5 device barriers. 512 blocks x 256 threads,
// __launch_bounds__(256,2) -> VGPR<=256 -> 2 blocks/CU; LDS 52.4KB -> 104.7KB/CU. All resident.
__global__ __launch_bounds__(256, 2) void mega_kernel(
        const float* __restrict__ x,
        const float* __restrict__ Wr, const float* __restrict__ Wo,
        const float* __restrict__ bo,
        const float* __restrict__ Wq, const float* __restrict__ Wk,
        const float* __restrict__ Wv, const float* __restrict__ gq,
        const float* __restrict__ gk, const float* __restrict__ gv,
        const float* __restrict__ memkv,
        float* __restrict__ rn,
        float* __restrict__ rowft, float* __restrict__ colft,
        float* __restrict__ Srow, float* __restrict__ Scol,
        float* __restrict__ WT,
        float* __restrict__ Qb, float* __restrict__ Kb, float* __restrict__ Vb,
        float* __restrict__ AO, float* __restrict__ Rr, float* __restrict__ Ccv,
        float* __restrict__ WfT2, float* __restrict__ bfb,
        float* __restrict__ out, int* __restrict__ bar) {
    __shared__ __align__(16) float lds[13088];
    const int tid = threadIdx.x;
    const int w = tid >> 6, lane = tid & 63;

    // ---------- P0: rn direct (400) + WfT2 (192) + WT (288) = 880 units ----------
    for (int u = blockIdx.x; u < 880; u += NBLK) {
        if (u < 400) {
            // rn: 64 float4-positions; wave w covers c in [w*48, w*48+48)
            float4* sp4 = reinterpret_cast<float4*>(lds);   // [4][64]
            int g4 = u * 64 + lane;
            int b = g4 / 6400, nm4 = g4 - b * 6400;
            const float* xb = x + (size_t)b * (C_ * NM_) + (size_t)nm4 * 4
                                + (size_t)(w * 48) * NM_;
            float4 s = make_float4(0.f, 0.f, 0.f, 0.f);
            #pragma unroll 16
            for (int cc = 0; cc < 48; cc++) {
                float4 v = *reinterpret_cast<const float4*>(xb + (size_t)cc * NM_);
                s.x += v.x * v.x; s.y += v.y * v.y; s.z += v.z * v.z; s.w += v.w * v.w;
            }
            sp4[w * 64 + lane] = s;
            __syncthreads();
            if (tid < 64) {
                float4 a = sp4[tid], b2 = sp4[64 + tid], c2 = sp4[128 + tid], d2 = sp4[192 + tid];
                float4 r;
                r.x = SQRT_C / fmaxf(sqrtf(a.x + b2.x + c2.x + d2.x), 1e-12f);
                r.y = SQRT_C / fmaxf(sqrtf(a.y + b2.y + c2.y + d2.y), 1e-12f);
                r.z = SQRT_C / fmaxf(sqrtf(a.z + b2.z + c2.z + d2.z), 1e-12f);
                r.w = SQRT_C / fmaxf(sqrtf(a.w + b2.w + c2.w + d2.w), 1e-12f);
                *reinterpret_cast<float4*>(rn + (size_t)(u * 64 + tid) * 4) = r;
            }
            __syncthreads();
        } else if (u < 592) {
            // fused (Wr @ Wo) weight, [pair][hd] layout: 2 pairs per unit
            int pair = (u - 400) * 2 + (tid >> 7);
            int hd = tid & 127;
            int t = pair / 192, dch = pair % 192;
            const float* wr = Wr + dch * 384 + t * 192;
            float acc = 0.f;
            for (int c = 0; c < 192; c++) acc += wr[c] * Wo[c * 128 + hd];
            WfT2[pair * 128 + hd] = acc;
            if (hd == 0) {
                float sb = 0.f;
                for (int c = 0; c < 192; c++) sb += wr[c] * bo[c];
                bfb[pair] = sb;
            }
        } else {
            // g-folded Wq/Wk/Wv in natural [hd][c] layout
            int g = (u - 592) * 256 + tid;      // < 73728
            int mat = g / 24576, r2 = g - mat * 24576;
            const float* W  = (mat == 0) ? Wq : ((mat == 1) ? Wk : Wv);
            const float* gp = (mat == 0) ? gq : ((mat == 1) ? gk : gv);
            WT[g] = gp[r2 % 192] * W[r2];
        }
    }
    gridbar(bar + 0);

    // ---------- P1: rowft/colft + Srow/Scol per (b,c) plane, no shuffles ----------
    for (int u = blockIdx.x; u < 768; u += NBLK) {
        int bc = u, b = bc / C_;
        const float* xp = x + (size_t)bc * NM_;
        const float* rp = rn + (size_t)b * NM_;
        if (tid < 160) {
            int m = tid;
            float cs = 0.f, cw = 0.f;
            #pragma unroll 8
            for (int n = 0; n < 160; n++) {
                float xv = xp[n * 160 + m], rv = rp[n * 160 + m];
                cs += xv; cw += xv * rv;
            }
            colft[bc * M_ + m] = cs * (1.0f / 160.0f);
            Scol[bc * M_ + m] = cw;
            // row pass (plane is L2-warm from col pass)
            const float* xr = xp + m * 160;
            const float* rr = rp + m * 160;
            float4 a = make_float4(0.f, 0.f, 0.f, 0.f);
            float4 bw = make_float4(0.f, 0.f, 0.f, 0.f);
            #pragma unroll 8
            for (int i = 0; i < 40; i++) {
                float4 xv = *reinterpret_cast<const float4*>(xr + i * 4);
                float4 rv = *reinterpret_cast<const float4*>(rr + i * 4);
                a.x += xv.x; a.y += xv.y; a.z += xv.z; a.w += xv.w;
                bw.x += xv.x * rv.x; bw.y += xv.y * rv.y;
                bw.z += xv.z * rv.z; bw.w += xv.w * rv.w;
            }
            rowft[bc * N_ + m] = (a.x + a.y + a.z + a.w) * (1.0f / 160.0f);
            Srow[bc * N_ + m] = bw.x + bw.y + bw.z + bw.w;
        }
    }
    gridbar(bar + 1);

    // ---------- P2: Q/K/Vsum projections with fused per-position RMS ----------
    for (int u = blockIdx.x; u < 960; u += NBLK) {
        float* in_s = lds;          // [4][196]
        float* sc_s = lds + 784;    // [4]
        int pt = u % 40, rest = u / 40;
        int mat = rest % 3; int r2 = rest / 3;
        int t = r2 % 2, b = r2 / 2;
        const float* src; float* dst;
        if (mat == 0)      { src = (t == 0) ? rowft : colft; dst = Qb; }
        else if (mat == 1) { src = (t == 0) ? colft : rowft; dst = Kb; }
        else               { src = (t == 0) ? Scol  : Srow;  dst = Vb; }
        const float* Wt = WT + mat * 24576;
        for (int idx = tid; idx < 768; idx += 256) {
            int c = idx >> 2, p = idx & 3;
            in_s[p * 196 + c] = src[(b * C_ + c) * 160 + pt * 4 + p];
        }
        __syncthreads();
        if (mat < 2) {
            float v0 = in_s[w * 196 + lane];
            float v1 = in_s[w * 196 + lane + 64];
            float v2 = in_s[w * 196 + lane + 128];
            float ssq = wred_sum(v0 * v0 + v1 * v1 + v2 * v2);
            if (lane == 0) sc_s[w] = SQRT_C / fmaxf(sqrtf(ssq), 1e-12f);
        } else {
            if (tid < 4) sc_s[tid] = 1.0f;
        }
        __syncthreads();
        int hd = tid & 127, p0 = (tid >> 7) * 2;
        const float* wp = Wt + hd * 192;
        const float* i0p = &in_s[p0 * 196];
        const float* i1p = &in_s[(p0 + 1) * 196];
        float a0 = 0.f, a1 = 0.f;
        #pragma unroll 4
        for (int c0 = 0; c0 < 192; c0 += 4) {
            float4 wv = *reinterpret_cast<const float4*>(wp + c0);
            float4 u0 = *reinterpret_cast<const float4*>(i0p + c0);
            float4 u1 = *reinterpret_cast<const float4*>(i1p + c0);
            a0 += wv.x * u0.x + wv.y * u0.y + wv.z * u0.z + wv.w * u0.w;
            a1 += wv.x * u1.x + wv.y * u1.y + wv.z * u1.z + wv.w * u1.w;
        }
        int posbase = (b * 2 + t) * 160 + pt * 4 + p0;
        dst[(size_t)posbase * 128 + hd]       = a0 * sc_s[p0];
        dst[(size_t)(posbase + 1) * 128 + hd] = a1 * sc_s[p0 + 1];
        __syncthreads();   // WAR before next unit reuses in_s
    }
    gridbar(bar + 2);

    // ---------- P3: attention ----------
    for (int u = blockIdx.x; u < 640; u += NBLK) {
        float* k_s = lds;            // [160][36]
        float* v_s = lds + 5760;     // [32][172]
        float* q_s = lds + 11264;    // [8][36]
        float* e_s = lds + 11552;    // [8][160]
        float* mk  = lds + 12832;    // [128]
        float* mv  = lds + 12960;    // [128]
        int qt = u % 20; int r = u / 20;
        int h = r & 3; r >>= 2;
        int t = r & 1; int b = r >> 1;
        int btbase = ((b * 2 + t) * 160) * 128 + h * 32;
        for (int idx = tid; idx < 1280; idx += 256) {
            int k = idx >> 3, dq = idx & 7;
            float4 kv = *reinterpret_cast<const float4*>(Kb + btbase + k * 128 + dq * 4);
            *reinterpret_cast<float4*>(&k_s[k * 36 + dq * 4]) = kv;
            float4 vv = *reinterpret_cast<const float4*>(Vb + btbase + k * 128 + dq * 4);
            v_s[(dq * 4 + 0) * 172 + k] = vv.x;
            v_s[(dq * 4 + 1) * 172 + k] = vv.y;
            v_s[(dq * 4 + 2) * 172 + k] = vv.z;
            v_s[(dq * 4 + 3) * 172 + k] = vv.w;
        }
        if (tid < 64) {
            int q = tid >> 3, dq = tid & 7;
            *reinterpret_cast<float4*>(&q_s[q * 36 + dq * 4]) =
                *reinterpret_cast<const float4*>(Qb + btbase + (qt * 8 + q) * 128 + dq * 4);
        }
        if (tid < 128) {
            mk[tid] = memkv[h * 128 + tid];
            mv[tid] = memkv[512 + h * 128 + tid];
        }
        __syncthreads();
        float4 kr0[8], kr1[8], kr2[8];
        #pragma unroll
        for (int dq = 0; dq < 8; dq++) {
            kr0[dq] = *reinterpret_cast<const float4*>(&k_s[lane * 36 + dq * 4]);
            kr1[dq] = *reinterpret_cast<const float4*>(&k_s[(lane + 64) * 36 + dq * 4]);
            if (lane < 32) kr2[dq] = *reinterpret_cast<const float4*>(&k_s[(lane + 128) * 36 + dq * 4]);
            else           kr2[dq] = make_float4(0.f, 0.f, 0.f, 0.f);
        }
        float p;
        {
            int pj = lane >> 3, qi = pj >> 2, j = pj & 3;
            int db = (lane & 7) * 4;
            float4 qv = *reinterpret_cast<const float4*>(&q_s[(w * 2 + qi) * 36 + db]);
            float4 mkv = *reinterpret_cast<const float4*>(&mk[j * 32 + db]);
            p = qv.x * mkv.x + qv.y * mkv.y + qv.z * mkv.z + qv.w * mkv.w;
            p += __shfl_xor(p, 1, 64); p += __shfl_xor(p, 2, 64); p += __shfl_xor(p, 4, 64);
            p *= SCALE_;
        }
        float sm[2][4];
        #pragma unroll
        for (int j = 0; j < 4; j++) {
            sm[0][j] = __shfl(p, j * 8, 64);
            sm[1][j] = __shfl(p, 32 + j * 8, 64);
        }
        int dpv = lane & 31;
        float Zq[2], accm[2];
        #pragma unroll
        for (int qi = 0; qi < 2; qi++) {
            const float* qrow = &q_s[(w * 2 + qi) * 36];
            float s0 = 0.f, s1 = 0.f, s2 = 0.f;
            #pragma unroll
            for (int dq = 0; dq < 8; dq++) {
                float4 qv = *reinterpret_cast<const float4*>(qrow + dq * 4);
                s0 += qv.x * kr0[dq].x + qv.y * kr0[dq].y + qv.z * kr0[dq].z + qv.w * kr0[dq].w;
                s1 += qv.x * kr1[dq].x + qv.y * kr1[dq].y + qv.z * kr1[dq].z + qv.w * kr1[dq].w;
                s2 += qv.x * kr2[dq].x + qv.y * kr2[dq].y + qv.z * kr2[dq].z + qv.w * kr2[dq].w;
            }
            s0 *= SCALE_; s1 *= SCALE_;
            s2 = (lane < 32) ? s2 * SCALE_ : -1e30f;
            float mx = fmaxf(fmaxf(s0, s1), s2);
            mx = fmaxf(mx, fmaxf(fmaxf(sm[qi][0], sm[qi][1]), fmaxf(sm[qi][2], sm[qi][3])));
            mx = wred_max(mx);
            float e0 = __expf(s0 - mx), e1 = __expf(s1 - mx);
            float e2 = (lane < 32) ? __expf(s2 - mx) : 0.f;
            int eb = (w * 2 + qi) * 160;
            e_s[eb + lane] = e0; e_s[eb + 64 + lane] = e1;
            if (lane < 32) e_s[eb + 128 + lane] = e2;
            float esum = wred_sum(e0 + e1 + e2);
            float em0 = __expf(sm[qi][0] - mx), em1 = __expf(sm[qi][1] - mx);
            float em2 = __expf(sm[qi][2] - mx), em3 = __expf(sm[qi][3] - mx);
            Zq[qi] = (em0 + em1 + em2 + em3) + 160.0f * esum;
            accm[qi] = em0 * mv[dpv] + em1 * mv[32 + dpv] + em2 * mv[64 + dpv] + em3 * mv[96 + dpv];
        }
        int half = lane >> 5, k0 = half * 80;
        const float* vrow = &v_s[dpv * 172 + k0];
        const float* e0p = &e_s[(w * 2) * 160 + k0];
        const float* e1p = &e_s[(w * 2 + 1) * 160 + k0];
        float a0 = 0.f, a1 = 0.f;
        #pragma unroll 4
        for (int kk = 0; kk < 80; kk += 4) {
            float4 vv = *reinterpret_cast<const float4*>(vrow + kk);
            float4 e0 = *reinterpret_cast<const float4*>(e0p + kk);
            float4 e1 = *reinterpret_cast<const float4*>(e1p + kk);
            a0 += e0.x * vv.x + e0.y * vv.y + e0.z * vv.z + e0.w * vv.w;
            a1 += e1.x * vv.x + e1.y * vv.y + e1.z * vv.z + e1.w * vv.w;
        }
        a0 += __shfl_down(a0, 32, 64);
        a1 += __shfl_down(a1, 32, 64);
        if (lane < 32) {
            AO[btbase + (qt * 8 + w * 2 + 0) * 128 + lane] = (accm[0] + a0) / Zq[0];
            AO[btbase + (qt * 8 + w * 2 + 1) * 128 + lane] = (accm[1] + a1) / Zq[1];
        }
        __syncthreads();   // WAR before next unit reuses k_s/v_s
    }
    gridbar(bar + 3);

    // ---------- P4: fused (Wr@Wo) output projection ----------
    for (int u = blockIdx.x; u < 640; u += NBLK) {
        float* ao_s = lds;           // [2*128]
        int pt = u % 80, rest = u / 80;
        int t = rest & 1, b = rest >> 1;
        ao_s[tid] = AO[(size_t)((b * 2 + t) * 160 + pt * 2 + (tid >> 7)) * 128 + (tid & 127)];
        __syncthreads();
        if (tid < 192) {
            int tofs = t * 192 + tid;
            const float* wp = WfT2 + tofs * 128;
            float a0 = 0.f, a1 = 0.f;
            #pragma unroll 8
            for (int hd = 0; hd < 128; hd += 4) {
                float4 w4 = *reinterpret_cast<const float4*>(wp + hd);
                float4 x0 = *reinterpret_cast<const float4*>(&ao_s[hd]);
                float4 x1 = *reinterpret_cast<const float4*>(&ao_s[128 + hd]);
                a0 += w4.x * x0.x + w4.y * x0.y + w4.z * x0.z + w4.w * x0.w;
                a1 += w4.x * x1.x + w4.y * x1.y + w4.z * x1.z + w4.w * x1.w;
            }
            float bb = bfb[tofs];
            float* dst = t ? Ccv : Rr;
            dst[(b * C_ + tid) * 160 + pt * 2 + 0] = a0 + bb;
            dst[(b * C_ + tid) * 160 + pt * 2 + 1] = a1 + bb;
        }
        __syncthreads();   // WAR before next unit reuses ao_s
    }
    gridbar(bar + 4);

    // ---------- P5: out[b,d,n,m] = Rr[b,d,n] + Ccv[b,d,m] ----------
    for (int u = blockIdx.x; u < 768; u += NBLK) {
        float* Rl = lds;             // [160]
        float* Cl = lds + 160;       // [160]
        if (tid < 160) { Rl[tid] = Rr[u * 160 + tid]; Cl[tid] = Ccv[u * 160 + tid]; }
        __syncthreads();
        float* base = out + (size_t)u * NM_;
        for (int idx = tid; idx < 160 * 40; idx += 256) {
            int n = idx / 40, m4 = idx - n * 40;
            float rv = Rl[n];
            float4 v;
            v.x = rv + Cl[m4 * 4 + 0];
            v.y = rv + Cl[m4 * 4 + 1];
            v.z = rv + Cl[m4 * 4 + 2];
            v.w = rv + Cl[m4 * 4 + 3];
            *reinterpret_cast<float4*>(base + n * 160 + m4 * 4) = v;
        }
        __syncthreads();   // WAR before next unit reuses Rl/Cl
    }
}

extern "C" void kernel_launch(void* const* d_in, const int* in_sizes, int n_in,
                              void* d_out, int out_size, void* d_ws, size_t ws_size,
                              hipStream_t stream) {
    const float* x    = (const float*)d_in[0];
    const float* gq   = (const float*)d_in[1];
    const float* gk   = (const float*)d_in[2];
    const float* gv   = (const float*)d_in[3];
    const float* Wq   = (const float*)d_in[4];
    const float* Wk   = (const float*)d_in[5];
    const float* Wv   = (const float*)d_in[6];
    const float* mkv  = (const float*)d_in[7];
    const float* Wo   = (const float*)d_in[8];
    const float* bo   = (const float*)d_in[9];
    const float* Wr   = (const float*)d_in[10];
    float* out = (float*)d_out;

    float* ws = (float*)d_ws;
    float* rn    = ws;                  // 102400
    float* rowft = rn    + 102400;      // 122880
    float* colft = rowft + 122880;
    float* Srow  = colft + 122880;
    float* Scol  = Srow  + 122880;
    float* WT    = Scol  + 122880;      // 73728
    float* Qb    = WT    + 73728;       // 163840
    float* Kb    = Qb    + 163840;
    float* Vb    = Kb    + 163840;
    float* AO    = Vb    + 163840;      // 163840
    float* Rr    = AO    + 163840;      // 122880
    float* Ccv   = Rr    + 122880;
    float* WfT   = Ccv   + 122880;      // 49152
    float* bfb   = WfT   + 49152;       // 384
    int*   bar   = (int*)(bfb + 384);   // 16 ints (5 used)

    hipMemsetAsync(bar, 0, 64, stream);
    mega_kernel<<<NBLK, 256, 0, stream>>>(x, Wr, Wo, bo, Wq, Wk, Wv, gq, gk, gv, mkv,
                                          rn, rowft, colft, Srow, Scol, WT,
                                          Qb, Kb, Vb, AO, Rr, Ccv, WfT, bfb,
                                          out, bar);
}